// Round 1
// baseline (59.101 us; speedup 1.0000x reference)
//
#include <hip/hip_runtime.h>

#define DEV __device__ __forceinline__

typedef __bf16 bf16x8 __attribute__((ext_vector_type(8)));
typedef float f32x4 __attribute__((ext_vector_type(4)));
typedef short s16x8 __attribute__((ext_vector_type(8)));
typedef unsigned short u16x4 __attribute__((ext_vector_type(4)));

constexpr int B_ = 8192;   // batch
constexpr int S_ = 3072;   // z dim
constexpr int H_ = 100;    // hidden
constexpr int NP_ = 128;   // padded hidden
constexpr int C_ = 1024;   // control dim
constexpr int KS_ = 64;    // K-step for GEMM1
constexpr int NIT_ = S_ / KS_;  // 48

// workspace layout (bytes)
constexpr size_t OFF_W1b = 0;                                   // [128 n][3072 k] bf16
constexpr size_t OFF_W2b = OFF_W1b + (size_t)NP_ * S_ * 2;      // [128 n][128 k] bf16
constexpr size_t OFF_W3c = OFF_W2b + (size_t)NP_ * NP_ * 2;     // [1024 n][128 k] bf16
constexpr size_t OFF_b3c = OFF_W3c + (size_t)C_ * NP_ * 2;      // [1024] f32
constexpr size_t OFF_h2b = OFF_b3c + (size_t)C_ * 4;            // [8192][128] bf16

DEV unsigned short f2bf(float f) {
  union { float f; unsigned u; } x; x.f = f;
  return (unsigned short)((x.u + 0x7FFFu + ((x.u >> 16) & 1u)) >> 16);
}

DEV float lambertw0(float x) {
  // principal branch, x >= 0; Halley from log1p start (matches reference fixed point)
  float w = log1pf(x);
#pragma unroll
  for (int i = 0; i < 10; ++i) {
    float ew = expf(w);
    float f = fmaf(w, ew, -x);
    float wp1 = w + 1.0f;
    float den = ew * wp1 - (w + 2.0f) * f / (2.0f * wp1);
    w = w - f / den;
  }
  return w;
}

// ---------------- prep: pack weights into bf16 n-major padded layouts ----------------
__global__ void k0_prep(const float* __restrict__ W1, const float* __restrict__ W2,
                        const float* __restrict__ W3, const float* __restrict__ b3,
                        unsigned char* __restrict__ ws) {
  int idx = blockIdx.x * 256 + threadIdx.x;
  constexpr int R1 = NP_ * S_;        // W1b elems
  constexpr int R2 = R1 + NP_ * NP_;  // + W2b
  constexpr int R3 = R2 + C_ * NP_;   // + W3cb
  constexpr int R4 = R3 + C_;         // + b3c
  if (idx < R1) {
    int n = idx / S_, k = idx - n * S_;
    float v = (n < H_) ? W1[(size_t)(k + 1) * H_ + n] : 0.0f;  // row 0 of W1 = t weights
    ((unsigned short*)(ws + OFF_W1b))[idx] = f2bf(v);
  } else if (idx < R2) {
    int j = idx - R1;
    int n = j >> 7, k = j & 127;
    float v = (n < H_ && k < H_) ? W2[(size_t)k * H_ + n] : 0.0f;
    ((unsigned short*)(ws + OFF_W2b))[j] = f2bf(v);
  } else if (idx < R3) {
    int j = idx - R2;
    int n = j >> 7, k = j & 127;
    float v = 0.0f;
    if (k < H_) {
      int a = n >> 2, cmp = n & 3;
      const float* row = W3 + (size_t)k * S_ + a * 12;
      v = (cmp == 0) ? 2.0f * (row[6] + row[7] + row[8]) : row[8 + cmp];  // /MASS = *2
    }
    ((unsigned short*)(ws + OFF_W3c))[j] = f2bf(v);
  } else if (idx < R4) {
    int n = idx - R3;
    int a = n >> 2, cmp = n & 3;
    const float* row = b3 + a * 12;
    float v = (cmp == 0) ? 2.0f * (row[6] + row[7] + row[8]) : row[8 + cmp];
    ((float*)(ws + OFF_b3c))[n] = v;
  }
}

// ---------------- K1: h2 = tanh(tanh([t,z]@W1+b1)@W2+b2) -> h2b (bf16) ----------------
// 256 blocks x 512 thr (8 waves). M_TILE=32 rows. wave w: m = w&1 (16-row tile),
// q = w>>1 (n-quarter: 2 of 8 n-tiles). LDS: A dbuf 2x4KB, B dbuf 2x16KB (reused as
// h1 tile 8KB + W2 tile 32KB for GEMM2). XOR swizzle ^((row&7)<<4) on all tiles.
__global__ __launch_bounds__(512, 2) void k1_mlp(
    const float* __restrict__ z, const float* __restrict__ t,
    const float* __restrict__ W1, const float* __restrict__ b1,
    const float* __restrict__ b2, const unsigned char* __restrict__ wsr,
    unsigned short* __restrict__ h2b) {
  __shared__ __align__(16) unsigned char lds[40 * 1024 + 128];
  unsigned char* ldsA = lds;         // 2 x 4KB (A tiles [32][64] bf16)
  unsigned char* ldsB = lds + 8192;  // 2 x 16KB (B tiles [128 n][64 k] bf16)
  float* t_lds = (float*)(lds + 40 * 1024);

  const int tid = threadIdx.x;
  const int lane = tid & 63;
  const int w = tid >> 6;
  const int m = w & 1;
  const int q = w >> 1;
  const int rowbase = blockIdx.x * 32;

  const unsigned short* W1b = (const unsigned short*)(wsr + OFF_W1b);
  const unsigned short* W2b = (const unsigned short*)(wsr + OFF_W2b);

  if (tid < 32) t_lds[tid] = t[rowbase + tid];

  float b1c[2], w1tc[2], b2c[2];
#pragma unroll
  for (int e = 0; e < 2; ++e) {
    int col = (q * 2 + e) * 16 + (lane & 15);
    bool ok = col < H_;
    b1c[e] = ok ? b1[col] : 0.0f;
    w1tc[e] = ok ? W1[col] : 0.0f;
    b2c[e] = ok ? b2[col] : 0.0f;
  }

  const int zrow = tid >> 4;        // 0..31
  const int zk4 = (tid & 15) * 4;   // 0..60
  const int r0 = m * 16 + (lane & 15);
  const int kb0 = (lane >> 4) * 16; // byte offset of this lane's k-octet

  f32x4 acc[2];
  acc[0] = f32x4{0.f, 0.f, 0.f, 0.f};
  acc[1] = f32x4{0.f, 0.f, 0.f, 0.f};

  // prologue: stage tile 0 into buf 0
  {
    float4 zv = *(const float4*)(z + (size_t)(rowbase + zrow) * S_ + zk4);
    u16x4 av; av[0] = f2bf(zv.x); av[1] = f2bf(zv.y); av[2] = f2bf(zv.z); av[3] = f2bf(zv.w);
    *(u16x4*)(ldsA + ((zrow * 128 + zk4 * 2) ^ ((zrow & 7) << 4))) = av;
#pragma unroll
    for (int s = 0; s < 2; ++s) {
      int p = s * 512 + tid;
      int n = p >> 3, k16 = p & 7;
      s16x8 v = *(const s16x8*)(W1b + (size_t)n * S_ + k16 * 8);
      *(s16x8*)(ldsB + ((n * 128 + k16 * 16) ^ ((n & 7) << 4))) = v;
    }
  }
  __syncthreads();

  for (int it = 0; it < NIT_; ++it) {
    const int cur = it & 1;
    unsigned char* Ac = ldsA + cur * 4096;
    unsigned char* Bc = ldsB + cur * 16384;
    const bool more = (it + 1 < NIT_);
    float4 zv;
    s16x8 bv0, bv1;
    if (more) {
      int kb = (it + 1) * KS_;
      zv = *(const float4*)(z + (size_t)(rowbase + zrow) * S_ + kb + zk4);
      {
        int p = tid;          int n = p >> 3, k16 = p & 7;
        bv0 = *(const s16x8*)(W1b + (size_t)n * S_ + kb + k16 * 8);
      }
      {
        int p = 512 + tid;    int n = p >> 3, k16 = p & 7;
        bv1 = *(const s16x8*)(W1b + (size_t)n * S_ + kb + k16 * 8);
      }
    }
    // compute current tile: 2 A-frags (k 0..31, 32..63), 2 n-tiles
    bf16x8 a0 = *(const bf16x8*)(Ac + ((r0 * 128 + 0 + kb0) ^ ((r0 & 7) << 4)));
    bf16x8 a1 = *(const bf16x8*)(Ac + ((r0 * 128 + 64 + kb0) ^ ((r0 & 7) << 4)));
#pragma unroll
    for (int e = 0; e < 2; ++e) {
      int n = (q * 2 + e) * 16 + (lane & 15);
      bf16x8 bb0 = *(const bf16x8*)(Bc + ((n * 128 + 0 + kb0) ^ ((n & 7) << 4)));
      bf16x8 bb1 = *(const bf16x8*)(Bc + ((n * 128 + 64 + kb0) ^ ((n & 7) << 4)));
      acc[e] = __builtin_amdgcn_mfma_f32_16x16x32_bf16(a0, bb0, acc[e], 0, 0, 0);
      acc[e] = __builtin_amdgcn_mfma_f32_16x16x32_bf16(a1, bb1, acc[e], 0, 0, 0);
    }
    if (more) {
      unsigned char* An = ldsA + (cur ^ 1) * 4096;
      unsigned char* Bn = ldsB + (cur ^ 1) * 16384;
      u16x4 av; av[0] = f2bf(zv.x); av[1] = f2bf(zv.y); av[2] = f2bf(zv.z); av[3] = f2bf(zv.w);
      *(u16x4*)(An + ((zrow * 128 + zk4 * 2) ^ ((zrow & 7) << 4))) = av;
      {
        int p = tid;          int n = p >> 3, k16 = p & 7;
        *(s16x8*)(Bn + ((n * 128 + k16 * 16) ^ ((n & 7) << 4))) = bv0;
      }
      {
        int p = 512 + tid;    int n = p >> 3, k16 = p & 7;
        *(s16x8*)(Bn + ((n * 128 + k16 * 16) ^ ((n & 7) << 4))) = bv1;
      }
    }
    __syncthreads();
  }

  // epilogue: h1 = tanh(acc + b1 + t*w1t) -> LDS [32 r][128 k] bf16 (A space)
#pragma unroll
  for (int e = 0; e < 2; ++e) {
    int col = (q * 2 + e) * 16 + (lane & 15);
#pragma unroll
    for (int i = 0; i < 4; ++i) {
      int r = m * 16 + ((lane >> 4) << 2) + i;
      float pre = acc[e][i] + b1c[e] + t_lds[r] * w1tc[e];
      *(unsigned short*)(ldsA + ((r * 256 + col * 2) ^ ((r & 7) << 4))) = f2bf(tanhf(pre));
    }
  }
  // stage W2 [128 n][128 k] bf16 into B space (32KB)
#pragma unroll
  for (int s = 0; s < 4; ++s) {
    int p = s * 512 + tid;
    int n = p >> 4, k16 = p & 15;
    s16x8 v = *(const s16x8*)(W2b + n * 128 + k16 * 8);
    *(s16x8*)(ldsB + ((n * 256 + k16 * 16) ^ ((n & 7) << 4))) = v;
  }
  __syncthreads();

  // GEMM2: K=128 (padded; pad contributes zeros)
  f32x4 acc2[2];
  acc2[0] = f32x4{0.f, 0.f, 0.f, 0.f};
  acc2[1] = f32x4{0.f, 0.f, 0.f, 0.f};
#pragma unroll
  for (int ks = 0; ks < 4; ++ks) {
    bf16x8 a = *(const bf16x8*)(ldsA + ((r0 * 256 + ks * 64 + kb0) ^ ((r0 & 7) << 4)));
#pragma unroll
    for (int e = 0; e < 2; ++e) {
      int n = (q * 2 + e) * 16 + (lane & 15);
      bf16x8 b = *(const bf16x8*)(ldsB + ((n * 256 + ks * 64 + kb0) ^ ((n & 7) << 4)));
      acc2[e] = __builtin_amdgcn_mfma_f32_16x16x32_bf16(a, b, acc2[e], 0, 0, 0);
    }
  }
#pragma unroll
  for (int e = 0; e < 2; ++e) {
    int col = (q * 2 + e) * 16 + (lane & 15);
#pragma unroll
    for (int i = 0; i < 4; ++i) {
      int r = m * 16 + ((lane >> 4) << 2) + i;
      float h = tanhf(acc2[e][i] + b2c[e]);   // pad cols: acc=0,b2c=0 -> 0
      h2b[(size_t)(rowbase + r) * NP_ + col] = f2bf(h);
    }
  }
}

// ---------------- K2: c = h2@W3c + b3c; s=||c||^2; k=f(W(s*256)); u=-k*c ----------------
// 256 blocks x 512 thr. wave w: m=w&1, q=w>>1 owns n-tiles {q,q+4} of each 8-tile chunk.
__global__ __launch_bounds__(512, 2) void k2_head(
    const unsigned char* __restrict__ wsr, float* __restrict__ uo) {
  __shared__ __align__(16) unsigned char ldsA[8192];        // h2 tile [32][128] bf16
  __shared__ __align__(16) unsigned char ldsB[2][32768];    // W3c chunk [128 n][128 k]
  __shared__ float s_part[32][4];
  __shared__ float k_lds[32];

  const int tid = threadIdx.x;
  const int lane = tid & 63;
  const int w = tid >> 6;
  const int m = w & 1;
  const int q = w >> 1;
  const int rowbase = blockIdx.x * 32;

  const unsigned short* h2b = (const unsigned short*)(wsr + OFF_h2b);
  const unsigned short* W3cb = (const unsigned short*)(wsr + OFF_W3c);
  const float* b3c = (const float*)(wsr + OFF_b3c);

  // stage A (32x128 bf16 = 8KB; one 16B chunk per thread)
  {
    int n = tid >> 4, k16 = tid & 15;
    s16x8 v = *(const s16x8*)(h2b + (size_t)(rowbase + n) * NP_ + k16 * 8);
    *(s16x8*)(ldsA + ((n * 256 + k16 * 16) ^ ((n & 7) << 4))) = v;
  }
  // stage chunk 0
#pragma unroll
  for (int s = 0; s < 4; ++s) {
    int p = s * 512 + tid;
    int n = p >> 4, k16 = p & 15;
    s16x8 v = *(const s16x8*)(W3cb + (size_t)n * NP_ + k16 * 8);
    *(s16x8*)(ldsB[0] + ((n * 256 + k16 * 16) ^ ((n & 7) << 4))) = v;
  }
  if (tid < 128) s_part[tid >> 2][tid & 3] = 0.0f;
  __syncthreads();

  const int r0 = m * 16 + (lane & 15);
  const int kb0 = (lane >> 4) * 16;
  bf16x8 af[4];
#pragma unroll
  for (int ks = 0; ks < 4; ++ks)
    af[ks] = *(const bf16x8*)(ldsA + ((r0 * 256 + ks * 64 + kb0) ^ ((r0 & 7) << 4)));

  f32x4 fr[16];
#pragma unroll
  for (int i = 0; i < 16; ++i) fr[i] = f32x4{0.f, 0.f, 0.f, 0.f};

#pragma unroll 8
  for (int ch = 0; ch < 8; ++ch) {
    const int cur = ch & 1;
    const bool more = ch < 7;
    s16x8 st0, st1, st2, st3;
    if (more) {
      int base = (ch + 1) * 128;
      { int p = tid;            int n = p >> 4, k16 = p & 15; st0 = *(const s16x8*)(W3cb + (size_t)(base + n) * NP_ + k16 * 8); }
      { int p = 512 + tid;      int n = p >> 4, k16 = p & 15; st1 = *(const s16x8*)(W3cb + (size_t)(base + n) * NP_ + k16 * 8); }
      { int p = 1024 + tid;     int n = p >> 4, k16 = p & 15; st2 = *(const s16x8*)(W3cb + (size_t)(base + n) * NP_ + k16 * 8); }
      { int p = 1536 + tid;     int n = p >> 4, k16 = p & 15; st3 = *(const s16x8*)(W3cb + (size_t)(base + n) * NP_ + k16 * 8); }
    }
#pragma unroll
    for (int e = 0; e < 2; ++e) {
      int nloc = (q + 4 * e) * 16 + (lane & 15);
#pragma unroll
      for (int ks = 0; ks < 4; ++ks) {
        bf16x8 b = *(const bf16x8*)(ldsB[cur] + ((nloc * 256 + ks * 64 + kb0) ^ ((nloc & 7) << 4)));
        fr[ch * 2 + e] = __builtin_amdgcn_mfma_f32_16x16x32_bf16(af[ks], b, fr[ch * 2 + e], 0, 0, 0);
      }
    }
    if (more) {
      unsigned char* Bn = ldsB[cur ^ 1];
      { int p = tid;        int n = p >> 4, k16 = p & 15; *(s16x8*)(Bn + ((n * 256 + k16 * 16) ^ ((n & 7) << 4))) = st0; }
      { int p = 512 + tid;  int n = p >> 4, k16 = p & 15; *(s16x8*)(Bn + ((n * 256 + k16 * 16) ^ ((n & 7) << 4))) = st1; }
      { int p = 1024 + tid; int n = p >> 4, k16 = p & 15; *(s16x8*)(Bn + ((n * 256 + k16 * 16) ^ ((n & 7) << 4))) = st2; }
      { int p = 1536 + tid; int n = p >> 4, k16 = p & 15; *(s16x8*)(Bn + ((n * 256 + k16 * 16) ^ ((n & 7) << 4))) = st3; }
    }
    __syncthreads();
  }

  // add folded bias b3c -> c values
#pragma unroll
  for (int fi = 0; fi < 16; ++fi) {
    int ch = fi >> 1, e = fi & 1;
    int col = (ch * 8 + q + 4 * e) * 16 + (lane & 15);
    float bc = b3c[col];
    fr[fi][0] += bc; fr[fi][1] += bc; fr[fi][2] += bc; fr[fi][3] += bc;
  }
  // per-row s = sum c^2 : per-lane partial -> 16-lane butterfly -> deterministic slots
#pragma unroll
  for (int i = 0; i < 4; ++i) {
    float v = 0.f;
#pragma unroll
    for (int fi = 0; fi < 16; ++fi) v += fr[fi][i] * fr[fi][i];
    v += __shfl_xor(v, 1);
    v += __shfl_xor(v, 2);
    v += __shfl_xor(v, 4);
    v += __shfl_xor(v, 8);
    if ((lane & 15) == 0) s_part[m * 16 + ((lane >> 4) << 2) + i][q] = v;
  }
  __syncthreads();
  if (tid < 32) {
    float s = s_part[tid][0] + s_part[tid][1] + s_part[tid][2] + s_part[tid][3];
    float kk = 0.0f;
    if (s > 0.0f) {
      float wv = lambertw0(s * 256.0f);       // x = s/(2*alpha), alpha=1/512
      kk = sqrtf(wv * 256.0f / s);            // k = sqrt(W/(2*alpha*s))
    }
    k_lds[tid] = kk;
  }
  __syncthreads();
#pragma unroll
  for (int fi = 0; fi < 16; ++fi) {
    int ch = fi >> 1, e = fi & 1;
    int col = (ch * 8 + q + 4 * e) * 16 + (lane & 15);
#pragma unroll
    for (int i = 0; i < 4; ++i) {
      int r = m * 16 + ((lane >> 4) << 2) + i;
      uo[(size_t)(rowbase + r) * C_ + col] = -k_lds[r] * fr[fi][i];
    }
  }
}

extern "C" void kernel_launch(void* const* d_in, const int* in_sizes, int n_in,
                              void* d_out, int out_size, void* d_ws, size_t ws_size,
                              hipStream_t stream) {
  const float* z  = (const float*)d_in[0];
  const float* t  = (const float*)d_in[1];
  const float* W1 = (const float*)d_in[2];
  const float* b1 = (const float*)d_in[3];
  const float* W2 = (const float*)d_in[4];
  const float* b2 = (const float*)d_in[5];
  const float* W3 = (const float*)d_in[6];
  const float* b3 = (const float*)d_in[7];
  float* out = (float*)d_out;
  unsigned char* ws = (unsigned char*)d_ws;

  constexpr int PREP_ELEMS = NP_ * S_ + NP_ * NP_ + C_ * NP_ + C_;
  k0_prep<<<(PREP_ELEMS + 255) / 256, 256, 0, stream>>>(W1, W2, W3, b3, ws);
  k1_mlp<<<B_ / 32, 512, 0, stream>>>(z, t, W1, b1, b2, ws,
                                      (unsigned short*)(ws + OFF_h2b));
  k2_head<<<B_ / 32, 512, 0, stream>>>(ws, out);
}

// Round 3
// 57.488 us; speedup vs baseline: 1.0281x; 1.0281x over previous
//
#include <hip/hip_runtime.h>

#define DEV __device__ __forceinline__

typedef __bf16 bf16x8 __attribute__((ext_vector_type(8)));
typedef float f32x4 __attribute__((ext_vector_type(4)));
typedef short s16x8 __attribute__((ext_vector_type(8)));
typedef unsigned short u16x4 __attribute__((ext_vector_type(4)));
typedef unsigned short u16x8 __attribute__((ext_vector_type(8)));

constexpr int B_ = 8192;   // batch
constexpr int S_ = 3072;   // z dim
constexpr int H_ = 100;    // hidden
constexpr int NP_ = 128;   // padded hidden
constexpr int C_ = 1024;   // control dim
constexpr int KS_ = 64;    // K-step for GEMM1
constexpr int NSPLIT_ = 4; // K-split factor
constexpr int KSP_ = S_ / NSPLIT_;       // 768 per split
constexpr int NIT_ = KSP_ / KS_;         // 12 iters per block

// workspace layout (bytes)
constexpr size_t OFF_W1b = 0;                                   // [128 n][3072 k] bf16
constexpr size_t OFF_W2b = OFF_W1b + (size_t)NP_ * S_ * 2;      // [128 n][128 k] bf16
constexpr size_t OFF_W3c = OFF_W2b + (size_t)NP_ * NP_ * 2;     // [1024 n][128 k] bf16
constexpr size_t OFF_b3c = OFF_W3c + (size_t)C_ * NP_ * 2;      // [1024] f32
constexpr size_t OFF_h2b = OFF_b3c + (size_t)C_ * 4;            // [8192][128] bf16

DEV unsigned short f2bf(float f) {
  union { float f; unsigned u; } x; x.f = f;
  return (unsigned short)((x.u + 0x7FFFu + ((x.u >> 16) & 1u)) >> 16);
}

DEV float lambertw0(float x) {
  float w = log1pf(x);
#pragma unroll
  for (int i = 0; i < 10; ++i) {
    float ew = expf(w);
    float f = fmaf(w, ew, -x);
    float wp1 = w + 1.0f;
    float den = ew * wp1 - (w + 2.0f) * f / (2.0f * wp1);
    w = w - f / den;
  }
  return w;
}

// ---------------- prep: pack weights into bf16 n-major padded layouts ----------------
__global__ void k0_prep(const float* __restrict__ W1, const float* __restrict__ W2,
                        const float* __restrict__ W3, const float* __restrict__ b3,
                        unsigned char* __restrict__ ws) {
  int idx = blockIdx.x * 256 + threadIdx.x;
  constexpr int R1 = NP_ * S_;
  constexpr int R2 = R1 + NP_ * NP_;
  constexpr int R3 = R2 + C_ * NP_;
  constexpr int R4 = R3 + C_;
  if (idx < R1) {
    int n = idx / S_, k = idx - n * S_;
    float v = (n < H_) ? W1[(size_t)(k + 1) * H_ + n] : 0.0f;  // row 0 of W1 = t weights
    ((unsigned short*)(ws + OFF_W1b))[idx] = f2bf(v);
  } else if (idx < R2) {
    int j = idx - R1;
    int n = j >> 7, k = j & 127;
    float v = (n < H_ && k < H_) ? W2[(size_t)k * H_ + n] : 0.0f;
    ((unsigned short*)(ws + OFF_W2b))[j] = f2bf(v);
  } else if (idx < R3) {
    int j = idx - R2;
    int n = j >> 7, k = j & 127;
    float v = 0.0f;
    if (k < H_) {
      int a = n >> 2, cmp = n & 3;
      const float* row = W3 + (size_t)k * S_ + a * 12;
      v = (cmp == 0) ? 2.0f * (row[6] + row[7] + row[8]) : row[8 + cmp];  // /MASS = *2
    }
    ((unsigned short*)(ws + OFF_W3c))[j] = f2bf(v);
  } else if (idx < R4) {
    int n = idx - R3;
    int a = n >> 2, cmp = n & 3;
    const float* row = b3 + a * 12;
    float v = (cmp == 0) ? 2.0f * (row[6] + row[7] + row[8]) : row[8 + cmp];
    ((float*)(ws + OFF_b3c))[n] = v;
  }
}

// ---------------- K1: partial[h] = z[:, h*768:(h+1)*768] @ W1b[:, same]^T ----------------
// grid 1024 = 256 row-tiles x 4 K-quarters; 256 thr (4 waves); 40KB LDS -> 4 blocks/CU.
// wave w: m = w&1 (16-row half), q = w>>1 (64-col half; 4 n-tiles).
__global__ __launch_bounds__(256, 4) void k1_gemm1(
    const float* __restrict__ z, const unsigned char* __restrict__ wsr,
    float* __restrict__ part) {
  __shared__ __align__(16) unsigned char lds[40 * 1024];
  unsigned char* ldsA = lds;          // 2 x 4KB  ([32 r][64 k] bf16, swizzled)
  unsigned char* ldsB = lds + 8192;   // 2 x 16KB ([128 n][64 k] bf16, swizzled)

  const int tid = threadIdx.x;
  const int lane = tid & 63;
  const int w = tid >> 6;
  const int m = w & 1;
  const int q = w >> 1;
  const int bid = blockIdx.x;
  const int rt = bid >> 2;
  const int h = bid & 3;
  const int rowbase = rt * 32;
  const int k0 = h * KSP_;

  const unsigned short* W1b = (const unsigned short*)(wsr + OFF_W1b);

  // staging addresses
  const int zrow = tid >> 3;              // 0..31
  const int zk8 = (tid & 7) * 8;          // 0..56 (8 floats per thread)
  const float* zp = z + (size_t)(rowbase + zrow) * S_ + k0 + zk8;
  const int bn = tid >> 3;                // 0..31 (+ s*32)
  const int bk16 = (tid & 7) * 8;         // elem offset of 8-bf16 chunk
  const unsigned short* bp = W1b + (size_t)bn * S_ + k0 + bk16;

  const int aswz = ((zrow & 7) << 4);
  const int abyte = zrow * 128 + zk8 * 2;
  const int bswz = ((bn & 7) << 4);
  const int bbyte0 = bn * 128 + bk16 * 2;

  const int r0 = m * 16 + (lane & 15);
  const int kb0 = (lane >> 4) * 16;

  f32x4 acc[4];
#pragma unroll
  for (int e = 0; e < 4; ++e) acc[e] = f32x4{0.f, 0.f, 0.f, 0.f};

  // prologue: stage tile 0 into buf 0
  {
    float4 za = *(const float4*)(zp);
    float4 zb = *(const float4*)(zp + 4);
    u16x8 av;
    av[0] = f2bf(za.x); av[1] = f2bf(za.y); av[2] = f2bf(za.z); av[3] = f2bf(za.w);
    av[4] = f2bf(zb.x); av[5] = f2bf(zb.y); av[6] = f2bf(zb.z); av[7] = f2bf(zb.w);
    *(u16x8*)(ldsA + (abyte ^ aswz)) = av;
#pragma unroll
    for (int s = 0; s < 4; ++s) {
      s16x8 v = *(const s16x8*)(bp + (size_t)(s * 32) * S_);
      *(s16x8*)(ldsB + ((bbyte0 + s * 32 * 128) ^ bswz)) = v;
    }
  }
  __syncthreads();

  for (int it = 0; it < NIT_; ++it) {
    const int cur = it & 1;
    unsigned char* Ac = ldsA + cur * 4096;
    unsigned char* Bc = ldsB + cur * 16384;
    const bool more = (it + 1 < NIT_);
    float4 za, zb;
    s16x8 bv0, bv1, bv2, bv3;
    if (more) {
      const int ko = (it + 1) * KS_;
      za = *(const float4*)(zp + ko);
      zb = *(const float4*)(zp + ko + 4);
      bv0 = *(const s16x8*)(bp + ko);
      bv1 = *(const s16x8*)(bp + ko + (size_t)32 * S_);
      bv2 = *(const s16x8*)(bp + ko + (size_t)64 * S_);
      bv3 = *(const s16x8*)(bp + ko + (size_t)96 * S_);
    }
    // compute current tile
    bf16x8 a0 = *(const bf16x8*)(Ac + ((r0 * 128 + 0 + kb0) ^ ((r0 & 7) << 4)));
    bf16x8 a1 = *(const bf16x8*)(Ac + ((r0 * 128 + 64 + kb0) ^ ((r0 & 7) << 4)));
#pragma unroll
    for (int e = 0; e < 4; ++e) {
      int n = q * 64 + e * 16 + (lane & 15);
      bf16x8 bb0 = *(const bf16x8*)(Bc + ((n * 128 + 0 + kb0) ^ ((n & 7) << 4)));
      bf16x8 bb1 = *(const bf16x8*)(Bc + ((n * 128 + 64 + kb0) ^ ((n & 7) << 4)));
      acc[e] = __builtin_amdgcn_mfma_f32_16x16x32_bf16(a0, bb0, acc[e], 0, 0, 0);
      acc[e] = __builtin_amdgcn_mfma_f32_16x16x32_bf16(a1, bb1, acc[e], 0, 0, 0);
    }
    if (more) {
      unsigned char* An = ldsA + (cur ^ 1) * 4096;
      unsigned char* Bn = ldsB + (cur ^ 1) * 16384;
      u16x8 av;
      av[0] = f2bf(za.x); av[1] = f2bf(za.y); av[2] = f2bf(za.z); av[3] = f2bf(za.w);
      av[4] = f2bf(zb.x); av[5] = f2bf(zb.y); av[6] = f2bf(zb.z); av[7] = f2bf(zb.w);
      *(u16x8*)(An + (abyte ^ aswz)) = av;
      *(s16x8*)(Bn + ((bbyte0 + 0 * 32 * 128) ^ bswz)) = bv0;
      *(s16x8*)(Bn + ((bbyte0 + 1 * 32 * 128) ^ bswz)) = bv1;
      *(s16x8*)(Bn + ((bbyte0 + 2 * 32 * 128) ^ bswz)) = bv2;
      *(s16x8*)(Bn + ((bbyte0 + 3 * 32 * 128) ^ bswz)) = bv3;
    }
    __syncthreads();
  }

  // write fp32 partial: part[h][rowbase+row][col]
  float* pout = part + (size_t)h * B_ * NP_;
#pragma unroll
  for (int e = 0; e < 4; ++e) {
    int col = q * 64 + e * 16 + (lane & 15);
#pragma unroll
    for (int i = 0; i < 4; ++i) {
      int r = m * 16 + ((lane >> 4) << 2) + i;
      pout[(size_t)(rowbase + r) * NP_ + col] = acc[e][i];
    }
  }
}

// ---------------- K2a: h2 = tanh(tanh(sum part + b1 + t*w1t) @ W2 + b2) -> h2b ----------
__global__ __launch_bounds__(256, 4) void k2a_mlp(
    const float* __restrict__ part, const float* __restrict__ t,
    const float* __restrict__ W1, const float* __restrict__ b1,
    const float* __restrict__ b2, const unsigned char* __restrict__ wsr,
    unsigned short* __restrict__ h2b) {
  __shared__ __align__(16) unsigned char ldsA[8192];   // h1 [32 r][128 k] bf16 swz
  __shared__ __align__(16) unsigned char ldsB[32768];  // W2 [128 n][128 k] bf16 swz

  const int tid = threadIdx.x;
  const int lane = tid & 63;
  const int w = tid >> 6;
  const int m = w & 1;
  const int q = w >> 1;
  const int rowbase = blockIdx.x * 32;

  const unsigned short* W2b = (const unsigned short*)(wsr + OFF_W2b);

  // phase 1: reduce partials + bias + t*w1t, tanh -> ldsA
  {
    const int row = tid >> 3;            // 0..31
    const int col0 = (tid & 7) * 16;     // 16 cols per thread
    const float* p0 = part + (size_t)(rowbase + row) * NP_ + col0;
    f32x4 v[4];
#pragma unroll
    for (int p = 0; p < 4; ++p) {
      v[p] = *(const f32x4*)(p0 + p * 4);
#pragma unroll
      for (int hh = 1; hh < NSPLIT_; ++hh) {
        f32x4 u = *(const f32x4*)(p0 + (size_t)hh * B_ * NP_ + p * 4);
        v[p][0] += u[0]; v[p][1] += u[1]; v[p][2] += u[2]; v[p][3] += u[3];
      }
    }
    const float tv = t[rowbase + row];
    u16x8 o0, o1;
#pragma unroll
    for (int j = 0; j < 16; ++j) {
      int col = col0 + j;
      float b1c = (col < H_) ? b1[col] : 0.0f;
      float w1t = (col < H_) ? W1[col] : 0.0f;
      float pre = v[j >> 2][j & 3] + b1c + tv * w1t;
      unsigned short hb = f2bf(tanhf(pre));
      if (j < 8) o0[j] = hb; else o1[j - 8] = hb;
    }
    const int sw = ((row & 7) << 4);
    *(u16x8*)(ldsA + ((row * 256 + col0 * 2) ^ sw)) = o0;
    *(u16x8*)(ldsA + ((row * 256 + (col0 + 8) * 2) ^ sw)) = o1;
  }
  // stage W2 tile: [128 n][128 k] bf16 = 2048 16B-chunks; 256 thr x 8 iters
#pragma unroll
  for (int s = 0; s < 8; ++s) {
    int p = s * 256 + tid;
    int n = p >> 4, k16 = p & 15;
    s16x8 v = *(const s16x8*)(W2b + n * 128 + k16 * 8);
    *(s16x8*)(ldsB + ((n * 256 + k16 * 16) ^ ((n & 7) << 4))) = v;
  }
  __syncthreads();

  // GEMM2: K=128
  const int r0 = m * 16 + (lane & 15);
  const int kb0 = (lane >> 4) * 16;
  f32x4 acc[4];
#pragma unroll
  for (int e = 0; e < 4; ++e) acc[e] = f32x4{0.f, 0.f, 0.f, 0.f};
#pragma unroll
  for (int ks = 0; ks < 4; ++ks) {
    bf16x8 a = *(const bf16x8*)(ldsA + ((r0 * 256 + ks * 64 + kb0) ^ ((r0 & 7) << 4)));
#pragma unroll
    for (int e = 0; e < 4; ++e) {
      int n = q * 64 + e * 16 + (lane & 15);
      bf16x8 b = *(const bf16x8*)(ldsB + ((n * 256 + ks * 64 + kb0) ^ ((n & 7) << 4)));
      acc[e] = __builtin_amdgcn_mfma_f32_16x16x32_bf16(a, b, acc[e], 0, 0, 0);
    }
  }
#pragma unroll
  for (int e = 0; e < 4; ++e) {
    int col = q * 64 + e * 16 + (lane & 15);
    float b2c = (col < H_) ? b2[col] : 0.0f;
#pragma unroll
    for (int i = 0; i < 4; ++i) {
      int r = m * 16 + ((lane >> 4) << 2) + i;
      float hh = tanhf(acc[e][i] + b2c);
      h2b[(size_t)(rowbase + r) * NP_ + col] = f2bf(hh);
    }
  }
}

// ---------------- K2b: c = h2@W3c + b3c; s=||c||^2; k=f(W(s*256)); u=-k*c ----------------
__global__ __launch_bounds__(512, 2) void k2_head(
    const unsigned char* __restrict__ wsr, float* __restrict__ uo) {
  __shared__ __align__(16) unsigned char ldsA[8192];        // h2 tile [32][128] bf16
  __shared__ __align__(16) unsigned char ldsB[2][32768];    // W3c chunk [128 n][128 k]
  __shared__ float s_part[32][4];
  __shared__ float k_lds[32];

  const int tid = threadIdx.x;
  const int lane = tid & 63;
  const int w = tid >> 6;
  const int m = w & 1;
  const int q = w >> 1;
  const int rowbase = blockIdx.x * 32;

  const unsigned short* h2b = (const unsigned short*)(wsr + OFF_h2b);
  const unsigned short* W3cb = (const unsigned short*)(wsr + OFF_W3c);
  const float* b3c = (const float*)(wsr + OFF_b3c);

  {
    int n = tid >> 4, k16 = tid & 15;
    s16x8 v = *(const s16x8*)(h2b + (size_t)(rowbase + n) * NP_ + k16 * 8);
    *(s16x8*)(ldsA + ((n * 256 + k16 * 16) ^ ((n & 7) << 4))) = v;
  }
#pragma unroll
  for (int s = 0; s < 4; ++s) {
    int p = s * 512 + tid;
    int n = p >> 4, k16 = p & 15;
    s16x8 v = *(const s16x8*)(W3cb + (size_t)n * NP_ + k16 * 8);
    *(s16x8*)(ldsB[0] + ((n * 256 + k16 * 16) ^ ((n & 7) << 4))) = v;
  }
  if (tid < 128) s_part[tid >> 2][tid & 3] = 0.0f;
  __syncthreads();

  const int r0 = m * 16 + (lane & 15);
  const int kb0 = (lane >> 4) * 16;
  bf16x8 af[4];
#pragma unroll
  for (int ks = 0; ks < 4; ++ks)
    af[ks] = *(const bf16x8*)(ldsA + ((r0 * 256 + ks * 64 + kb0) ^ ((r0 & 7) << 4)));

  f32x4 fr[16];
#pragma unroll
  for (int i = 0; i < 16; ++i) fr[i] = f32x4{0.f, 0.f, 0.f, 0.f};

#pragma unroll 8
  for (int ch = 0; ch < 8; ++ch) {
    const int cur = ch & 1;
    const bool more = ch < 7;
    s16x8 st0, st1, st2, st3;
    if (more) {
      int base = (ch + 1) * 128;
      { int p = tid;            int n = p >> 4, k16 = p & 15; st0 = *(const s16x8*)(W3cb + (size_t)(base + n) * NP_ + k16 * 8); }
      { int p = 512 + tid;      int n = p >> 4, k16 = p & 15; st1 = *(const s16x8*)(W3cb + (size_t)(base + n) * NP_ + k16 * 8); }
      { int p = 1024 + tid;     int n = p >> 4, k16 = p & 15; st2 = *(const s16x8*)(W3cb + (size_t)(base + n) * NP_ + k16 * 8); }
      { int p = 1536 + tid;     int n = p >> 4, k16 = p & 15; st3 = *(const s16x8*)(W3cb + (size_t)(base + n) * NP_ + k16 * 8); }
    }
#pragma unroll
    for (int e = 0; e < 2; ++e) {
      int nloc = (q + 4 * e) * 16 + (lane & 15);
#pragma unroll
      for (int ks = 0; ks < 4; ++ks) {
        bf16x8 b = *(const bf16x8*)(ldsB[cur] + ((nloc * 256 + ks * 64 + kb0) ^ ((nloc & 7) << 4)));
        fr[ch * 2 + e] = __builtin_amdgcn_mfma_f32_16x16x32_bf16(af[ks], b, fr[ch * 2 + e], 0, 0, 0);
      }
    }
    if (more) {
      unsigned char* Bn = ldsB[cur ^ 1];
      { int p = tid;        int n = p >> 4, k16 = p & 15; *(s16x8*)(Bn + ((n * 256 + k16 * 16) ^ ((n & 7) << 4))) = st0; }
      { int p = 512 + tid;  int n = p >> 4, k16 = p & 15; *(s16x8*)(Bn + ((n * 256 + k16 * 16) ^ ((n & 7) << 4))) = st1; }
      { int p = 1024 + tid; int n = p >> 4, k16 = p & 15; *(s16x8*)(Bn + ((n * 256 + k16 * 16) ^ ((n & 7) << 4))) = st2; }
      { int p = 1536 + tid; int n = p >> 4, k16 = p & 15; *(s16x8*)(Bn + ((n * 256 + k16 * 16) ^ ((n & 7) << 4))) = st3; }
    }
    __syncthreads();
  }

#pragma unroll
  for (int fi = 0; fi < 16; ++fi) {
    int ch = fi >> 1, e = fi & 1;
    int col = (ch * 8 + q + 4 * e) * 16 + (lane & 15);
    float bc = b3c[col];
    fr[fi][0] += bc; fr[fi][1] += bc; fr[fi][2] += bc; fr[fi][3] += bc;
  }
#pragma unroll
  for (int i = 0; i < 4; ++i) {
    float v = 0.f;
#pragma unroll
    for (int fi = 0; fi < 16; ++fi) v += fr[fi][i] * fr[fi][i];
    v += __shfl_xor(v, 1);
    v += __shfl_xor(v, 2);
    v += __shfl_xor(v, 4);
    v += __shfl_xor(v, 8);
    if ((lane & 15) == 0) s_part[m * 16 + ((lane >> 4) << 2) + i][q] = v;
  }
  __syncthreads();
  if (tid < 32) {
    float s = s_part[tid][0] + s_part[tid][1] + s_part[tid][2] + s_part[tid][3];
    float kk = 0.0f;
    if (s > 0.0f) {
      float wv = lambertw0(s * 256.0f);
      kk = sqrtf(wv * 256.0f / s);
    }
    k_lds[tid] = kk;
  }
  __syncthreads();
#pragma unroll
  for (int fi = 0; fi < 16; ++fi) {
    int ch = fi >> 1, e = fi & 1;
    int col = (ch * 8 + q + 4 * e) * 16 + (lane & 15);
#pragma unroll
    for (int i = 0; i < 4; ++i) {
      int r = m * 16 + ((lane >> 4) << 2) + i;
      uo[(size_t)(rowbase + r) * C_ + col] = -k_lds[r] * fr[fi][i];
    }
  }
}

extern "C" void kernel_launch(void* const* d_in, const int* in_sizes, int n_in,
                              void* d_out, int out_size, void* d_ws, size_t ws_size,
                              hipStream_t stream) {
  const float* z  = (const float*)d_in[0];
  const float* t  = (const float*)d_in[1];
  const float* W1 = (const float*)d_in[2];
  const float* b1 = (const float*)d_in[3];
  const float* W2 = (const float*)d_in[4];
  const float* b2 = (const float*)d_in[5];
  const float* W3 = (const float*)d_in[6];
  const float* b3 = (const float*)d_in[7];
  float* out = (float*)d_out;
  unsigned char* ws = (unsigned char*)d_ws;

  constexpr int PREP_ELEMS = NP_ * S_ + NP_ * NP_ + C_ * NP_ + C_;
  k0_prep<<<(PREP_ELEMS + 255) / 256, 256, 0, stream>>>(W1, W2, W3, b3, ws);
  // partials live in d_out (16 MB of the 32 MB output buffer; k2_head overwrites all)
  k1_gemm1<<<B_ / 32 * NSPLIT_, 256, 0, stream>>>(z, ws, out);
  k2a_mlp<<<B_ / 32, 256, 0, stream>>>(out, t, W1, b1, b2, ws,
                                       (unsigned short*)(ws + OFF_h2b));
  k2_head<<<B_ / 32, 512, 0, stream>>>(ws, out);
}

// Round 4
// 51.904 us; speedup vs baseline: 1.1387x; 1.1076x over previous
//
#include <hip/hip_runtime.h>

#define DEV __device__ __forceinline__

typedef __bf16 bf16x8 __attribute__((ext_vector_type(8)));
typedef float f32x4 __attribute__((ext_vector_type(4)));
typedef short s16x8 __attribute__((ext_vector_type(8)));
typedef unsigned short u16x8 __attribute__((ext_vector_type(8)));

constexpr int B_ = 8192;   // batch
constexpr int S_ = 3072;   // z dim
constexpr int H_ = 100;    // hidden
constexpr int NP_ = 128;   // padded hidden
constexpr int C_ = 1024;   // control dim
constexpr int KS_ = 64;    // K-step for GEMM1
constexpr int NSPLIT_ = 4; // K-split factor
constexpr int KSP_ = S_ / NSPLIT_;       // 768 per split
constexpr int NIT_ = KSP_ / KS_;         // 12 iters per block

// workspace layout (bytes)
constexpr size_t OFF_W1b = 0;                                   // [128 n][3072 k] bf16
constexpr size_t OFF_W2b = OFF_W1b + (size_t)NP_ * S_ * 2;      // [128 n][128 k] bf16
constexpr size_t OFF_W3c = OFF_W2b + (size_t)NP_ * NP_ * 2;     // [1024 n][128 k] bf16
constexpr size_t OFF_b3c = OFF_W3c + (size_t)C_ * NP_ * 2;      // [1024] f32
constexpr size_t OFF_part = OFF_b3c + (size_t)C_ * 4;           // [4][8192][128] f32 partials

DEV unsigned short f2bf(float f) {
  union { float f; unsigned u; } x; x.f = f;
  return (unsigned short)((x.u + 0x7FFFu + ((x.u >> 16) & 1u)) >> 16);
}

DEV float lambertw0(float x) {
  float w = log1pf(x);
#pragma unroll
  for (int i = 0; i < 10; ++i) {
    float ew = expf(w);
    float f = fmaf(w, ew, -x);
    float wp1 = w + 1.0f;
    float den = ew * wp1 - (w + 2.0f) * f / (2.0f * wp1);
    w = w - f / den;
  }
  return w;
}

// ---------------- prep: pack weights into bf16 n-major padded layouts ----------------
__global__ void k0_prep(const float* __restrict__ W1, const float* __restrict__ W2,
                        const float* __restrict__ W3, const float* __restrict__ b3,
                        unsigned char* __restrict__ ws) {
  int idx = blockIdx.x * 256 + threadIdx.x;
  constexpr int R1 = NP_ * S_;
  constexpr int R2 = R1 + NP_ * NP_;
  constexpr int R3 = R2 + C_ * NP_;
  constexpr int R4 = R3 + C_;
  if (idx < R1) {
    int n = idx / S_, k = idx - n * S_;
    float v = (n < H_) ? W1[(size_t)(k + 1) * H_ + n] : 0.0f;  // row 0 of W1 = t weights
    ((unsigned short*)(ws + OFF_W1b))[idx] = f2bf(v);
  } else if (idx < R2) {
    int j = idx - R1;
    int n = j >> 7, k = j & 127;
    float v = (n < H_ && k < H_) ? W2[(size_t)k * H_ + n] : 0.0f;
    ((unsigned short*)(ws + OFF_W2b))[j] = f2bf(v);
  } else if (idx < R3) {
    int j = idx - R2;
    int n = j >> 7, k = j & 127;
    float v = 0.0f;
    if (k < H_) {
      int a = n >> 2, cmp = n & 3;
      const float* row = W3 + (size_t)k * S_ + a * 12;
      v = (cmp == 0) ? 2.0f * (row[6] + row[7] + row[8]) : row[8 + cmp];  // /MASS = *2
    }
    ((unsigned short*)(ws + OFF_W3c))[j] = f2bf(v);
  } else if (idx < R4) {
    int n = idx - R3;
    int a = n >> 2, cmp = n & 3;
    const float* row = b3 + a * 12;
    float v = (cmp == 0) ? 2.0f * (row[6] + row[7] + row[8]) : row[8 + cmp];
    ((float*)(ws + OFF_b3c))[n] = v;
  }
}

// ---------------- K1: partial[h] = z[:, h*768:(h+1)*768] @ W1b[:, same]^T ----------------
// grid 1024 = 256 row-tiles x 4 K-quarters; 256 thr (4 waves); 40KB LDS -> 4 blocks/CU.
__global__ __launch_bounds__(256, 4) void k1_gemm1(
    const float* __restrict__ z, const unsigned char* __restrict__ wsr,
    float* __restrict__ part) {
  __shared__ __align__(16) unsigned char lds[40 * 1024];
  unsigned char* ldsA = lds;          // 2 x 4KB  ([32 r][64 k] bf16, swizzled)
  unsigned char* ldsB = lds + 8192;   // 2 x 16KB ([128 n][64 k] bf16, swizzled)

  const int tid = threadIdx.x;
  const int lane = tid & 63;
  const int w = tid >> 6;
  const int m = w & 1;
  const int q = w >> 1;
  const int bid = blockIdx.x;
  const int rt = bid >> 2;
  const int h = bid & 3;
  const int rowbase = rt * 32;
  const int k0 = h * KSP_;

  const unsigned short* W1b = (const unsigned short*)(wsr + OFF_W1b);

  const int zrow = tid >> 3;              // 0..31
  const int zk8 = (tid & 7) * 8;          // 0..56 (8 floats per thread)
  const float* zp = z + (size_t)(rowbase + zrow) * S_ + k0 + zk8;
  const int bn = tid >> 3;                // 0..31 (+ s*32)
  const int bk16 = (tid & 7) * 8;
  const unsigned short* bp = W1b + (size_t)bn * S_ + k0 + bk16;

  const int aswz = ((zrow & 7) << 4);
  const int abyte = zrow * 128 + zk8 * 2;
  const int bswz = ((bn & 7) << 4);
  const int bbyte0 = bn * 128 + bk16 * 2;

  const int r0 = m * 16 + (lane & 15);
  const int kb0 = (lane >> 4) * 16;

  f32x4 acc[4];
#pragma unroll
  for (int e = 0; e < 4; ++e) acc[e] = f32x4{0.f, 0.f, 0.f, 0.f};

  // prologue: stage tile 0 into buf 0
  {
    float4 za = *(const float4*)(zp);
    float4 zb = *(const float4*)(zp + 4);
    u16x8 av;
    av[0] = f2bf(za.x); av[1] = f2bf(za.y); av[2] = f2bf(za.z); av[3] = f2bf(za.w);
    av[4] = f2bf(zb.x); av[5] = f2bf(zb.y); av[6] = f2bf(zb.z); av[7] = f2bf(zb.w);
    *(u16x8*)(ldsA + (abyte ^ aswz)) = av;
#pragma unroll
    for (int s = 0; s < 4; ++s) {
      s16x8 v = *(const s16x8*)(bp + (size_t)(s * 32) * S_);
      *(s16x8*)(ldsB + ((bbyte0 + s * 32 * 128) ^ bswz)) = v;
    }
  }
  __syncthreads();

  for (int it = 0; it < NIT_; ++it) {
    const int cur = it & 1;
    unsigned char* Ac = ldsA + cur * 4096;
    unsigned char* Bc = ldsB + cur * 16384;
    const bool more = (it + 1 < NIT_);
    float4 za, zb;
    s16x8 bv0, bv1, bv2, bv3;
    if (more) {
      const int ko = (it + 1) * KS_;
      za = *(const float4*)(zp + ko);
      zb = *(const float4*)(zp + ko + 4);
      bv0 = *(const s16x8*)(bp + ko);
      bv1 = *(const s16x8*)(bp + ko + (size_t)32 * S_);
      bv2 = *(const s16x8*)(bp + ko + (size_t)64 * S_);
      bv3 = *(const s16x8*)(bp + ko + (size_t)96 * S_);
    }
    bf16x8 a0 = *(const bf16x8*)(Ac + ((r0 * 128 + 0 + kb0) ^ ((r0 & 7) << 4)));
    bf16x8 a1 = *(const bf16x8*)(Ac + ((r0 * 128 + 64 + kb0) ^ ((r0 & 7) << 4)));
#pragma unroll
    for (int e = 0; e < 4; ++e) {
      int n = q * 64 + e * 16 + (lane & 15);
      bf16x8 bb0 = *(const bf16x8*)(Bc + ((n * 128 + 0 + kb0) ^ ((n & 7) << 4)));
      bf16x8 bb1 = *(const bf16x8*)(Bc + ((n * 128 + 64 + kb0) ^ ((n & 7) << 4)));
      acc[e] = __builtin_amdgcn_mfma_f32_16x16x32_bf16(a0, bb0, acc[e], 0, 0, 0);
      acc[e] = __builtin_amdgcn_mfma_f32_16x16x32_bf16(a1, bb1, acc[e], 0, 0, 0);
    }
    if (more) {
      unsigned char* An = ldsA + (cur ^ 1) * 4096;
      unsigned char* Bn = ldsB + (cur ^ 1) * 16384;
      u16x8 av;
      av[0] = f2bf(za.x); av[1] = f2bf(za.y); av[2] = f2bf(za.z); av[3] = f2bf(za.w);
      av[4] = f2bf(zb.x); av[5] = f2bf(zb.y); av[6] = f2bf(zb.z); av[7] = f2bf(zb.w);
      *(u16x8*)(An + (abyte ^ aswz)) = av;
      *(s16x8*)(Bn + ((bbyte0 + 0 * 32 * 128) ^ bswz)) = bv0;
      *(s16x8*)(Bn + ((bbyte0 + 1 * 32 * 128) ^ bswz)) = bv1;
      *(s16x8*)(Bn + ((bbyte0 + 2 * 32 * 128) ^ bswz)) = bv2;
      *(s16x8*)(Bn + ((bbyte0 + 3 * 32 * 128) ^ bswz)) = bv3;
    }
    __syncthreads();
  }

  float* pout = part + (size_t)h * B_ * NP_;
#pragma unroll
  for (int e = 0; e < 4; ++e) {
    int col = q * 64 + e * 16 + (lane & 15);
#pragma unroll
    for (int i = 0; i < 4; ++i) {
      int r = m * 16 + ((lane >> 4) << 2) + i;
      pout[(size_t)(rowbase + r) * NP_ + col] = acc[e][i];
    }
  }
}

// ---------------- K2 fused: partial-reduce + GEMM2 + GEMM3 + LambertW head -------------
// 256 blocks x 512 thr (8 waves, 2 blocks/CU). Phase1: h1=tanh(sum part + b1 + t*w1t)
// -> ldsA. GEMM2 (W2 in ldsB[1]) -> h2 -> ldsA. GEMM3 streams W3c (8 dbuf chunks).
__global__ __launch_bounds__(512, 2) void k2_fused(
    const float* __restrict__ part, const float* __restrict__ t,
    const float* __restrict__ W1, const float* __restrict__ b1,
    const float* __restrict__ b2, const unsigned char* __restrict__ wsr,
    float* __restrict__ uo) {
  __shared__ __align__(16) unsigned char ldsA[8192];        // h1/h2 tile [32][128] bf16 swz
  __shared__ __align__(16) unsigned char ldsB[2][32768];    // W2 / W3c chunks
  __shared__ float s_part[32][4];
  __shared__ float k_lds[32];

  const int tid = threadIdx.x;
  const int lane = tid & 63;
  const int w = tid >> 6;
  const int m = w & 1;
  const int q = w >> 1;
  const int rowbase = blockIdx.x * 32;

  const unsigned short* W2b = (const unsigned short*)(wsr + OFF_W2b);
  const unsigned short* W3cb = (const unsigned short*)(wsr + OFF_W3c);
  const float* b3c = (const float*)(wsr + OFF_b3c);

  // phase 1: reduce partials + b1 + t*w1t, tanh -> ldsA (h1)
  {
    const int row = tid >> 4;           // 0..31
    const int col0 = (tid & 15) * 8;    // 0..120
    const float* p0 = part + (size_t)(rowbase + row) * NP_ + col0;
    f32x4 v[2];
#pragma unroll
    for (int p = 0; p < 2; ++p) {
      v[p] = *(const f32x4*)(p0 + p * 4);
#pragma unroll
      for (int hh = 1; hh < NSPLIT_; ++hh) {
        f32x4 u2 = *(const f32x4*)(p0 + (size_t)hh * B_ * NP_ + p * 4);
        v[p][0] += u2[0]; v[p][1] += u2[1]; v[p][2] += u2[2]; v[p][3] += u2[3];
      }
    }
    const float tv = t[rowbase + row];
    u16x8 o;
#pragma unroll
    for (int j = 0; j < 8; ++j) {
      int col = col0 + j;
      float b1c = (col < H_) ? b1[col] : 0.0f;
      float w1t = (col < H_) ? W1[col] : 0.0f;
      float pre = v[j >> 2][j & 3] + b1c + tv * w1t;
      o[j] = f2bf(tanhf(pre));
    }
    *(u16x8*)(ldsA + ((row * 256 + col0 * 2) ^ ((row & 7) << 4))) = o;
  }
  // stage W2 -> ldsB[1], W3c chunk0 -> ldsB[0] (2048 16B-chunks each; 512 thr x 4)
#pragma unroll
  for (int s = 0; s < 4; ++s) {
    int p = s * 512 + tid;
    int n = p >> 4, k16 = p & 15;
    s16x8 v2 = *(const s16x8*)(W2b + n * 128 + k16 * 8);
    *(s16x8*)(ldsB[1] + ((n * 256 + k16 * 16) ^ ((n & 7) << 4))) = v2;
    s16x8 v3 = *(const s16x8*)(W3cb + (size_t)n * NP_ + k16 * 8);
    *(s16x8*)(ldsB[0] + ((n * 256 + k16 * 16) ^ ((n & 7) << 4))) = v3;
  }
  if (tid < 128) s_part[tid >> 2][tid & 3] = 0.0f;
  __syncthreads();

  const int r0 = m * 16 + (lane & 15);
  const int kb0 = (lane >> 4) * 16;

  // GEMM2: K=128, cols split over 8 waves as (q*2+e)*16
  f32x4 acc2[2];
  acc2[0] = f32x4{0.f, 0.f, 0.f, 0.f};
  acc2[1] = f32x4{0.f, 0.f, 0.f, 0.f};
#pragma unroll
  for (int ks = 0; ks < 4; ++ks) {
    bf16x8 a = *(const bf16x8*)(ldsA + ((r0 * 256 + ks * 64 + kb0) ^ ((r0 & 7) << 4)));
#pragma unroll
    for (int e = 0; e < 2; ++e) {
      int n = (q * 2 + e) * 16 + (lane & 15);
      bf16x8 b = *(const bf16x8*)(ldsB[1] + ((n * 256 + ks * 64 + kb0) ^ ((n & 7) << 4)));
      acc2[e] = __builtin_amdgcn_mfma_f32_16x16x32_bf16(a, b, acc2[e], 0, 0, 0);
    }
  }
  __syncthreads();   // all h1/W2 reads done
  // h2 = tanh(acc2 + b2) -> ldsA (pad cols: acc=0, b2c=0 -> 0)
#pragma unroll
  for (int e = 0; e < 2; ++e) {
    int col = (q * 2 + e) * 16 + (lane & 15);
    float b2c = (col < H_) ? b2[col] : 0.0f;
#pragma unroll
    for (int i = 0; i < 4; ++i) {
      int r = m * 16 + ((lane >> 4) << 2) + i;
      float hh = tanhf(acc2[e][i] + b2c);
      *(unsigned short*)(ldsA + ((r * 256 + col * 2) ^ ((r & 7) << 4))) = f2bf(hh);
    }
  }
  __syncthreads();   // h2 visible to all

  // GEMM3: c = h2 @ W3c + b3c, streaming 8 chunks of 128 cols
  bf16x8 af[4];
#pragma unroll
  for (int ks = 0; ks < 4; ++ks)
    af[ks] = *(const bf16x8*)(ldsA + ((r0 * 256 + ks * 64 + kb0) ^ ((r0 & 7) << 4)));

  f32x4 fr[16];
#pragma unroll
  for (int i = 0; i < 16; ++i) fr[i] = f32x4{0.f, 0.f, 0.f, 0.f};

#pragma unroll 8
  for (int ch = 0; ch < 8; ++ch) {
    const int cur = ch & 1;
    const bool more = ch < 7;
    s16x8 st0, st1, st2, st3;
    if (more) {
      int base = (ch + 1) * 128;
      { int p = tid;            int n = p >> 4, k16 = p & 15; st0 = *(const s16x8*)(W3cb + (size_t)(base + n) * NP_ + k16 * 8); }
      { int p = 512 + tid;      int n = p >> 4, k16 = p & 15; st1 = *(const s16x8*)(W3cb + (size_t)(base + n) * NP_ + k16 * 8); }
      { int p = 1024 + tid;     int n = p >> 4, k16 = p & 15; st2 = *(const s16x8*)(W3cb + (size_t)(base + n) * NP_ + k16 * 8); }
      { int p = 1536 + tid;     int n = p >> 4, k16 = p & 15; st3 = *(const s16x8*)(W3cb + (size_t)(base + n) * NP_ + k16 * 8); }
    }
#pragma unroll
    for (int e = 0; e < 2; ++e) {
      int nloc = (q + 4 * e) * 16 + (lane & 15);
#pragma unroll
      for (int ks = 0; ks < 4; ++ks) {
        bf16x8 b = *(const bf16x8*)(ldsB[cur] + ((nloc * 256 + ks * 64 + kb0) ^ ((nloc & 7) << 4)));
        fr[ch * 2 + e] = __builtin_amdgcn_mfma_f32_16x16x32_bf16(af[ks], b, fr[ch * 2 + e], 0, 0, 0);
      }
    }
    if (more) {
      unsigned char* Bn = ldsB[cur ^ 1];
      { int p = tid;        int n = p >> 4, k16 = p & 15; *(s16x8*)(Bn + ((n * 256 + k16 * 16) ^ ((n & 7) << 4))) = st0; }
      { int p = 512 + tid;  int n = p >> 4, k16 = p & 15; *(s16x8*)(Bn + ((n * 256 + k16 * 16) ^ ((n & 7) << 4))) = st1; }
      { int p = 1024 + tid; int n = p >> 4, k16 = p & 15; *(s16x8*)(Bn + ((n * 256 + k16 * 16) ^ ((n & 7) << 4))) = st2; }
      { int p = 1536 + tid; int n = p >> 4, k16 = p & 15; *(s16x8*)(Bn + ((n * 256 + k16 * 16) ^ ((n & 7) << 4))) = st3; }
    }
    __syncthreads();
  }

  // bias, s = ||c||^2, k = f(W(s*256)), u = -k*c
#pragma unroll
  for (int fi = 0; fi < 16; ++fi) {
    int ch = fi >> 1, e = fi & 1;
    int col = (ch * 8 + q + 4 * e) * 16 + (lane & 15);
    float bc = b3c[col];
    fr[fi][0] += bc; fr[fi][1] += bc; fr[fi][2] += bc; fr[fi][3] += bc;
  }
#pragma unroll
  for (int i = 0; i < 4; ++i) {
    float v = 0.f;
#pragma unroll
    for (int fi = 0; fi < 16; ++fi) v += fr[fi][i] * fr[fi][i];
    v += __shfl_xor(v, 1);
    v += __shfl_xor(v, 2);
    v += __shfl_xor(v, 4);
    v += __shfl_xor(v, 8);
    if ((lane & 15) == 0) s_part[m * 16 + ((lane >> 4) << 2) + i][q] = v;
  }
  __syncthreads();
  if (tid < 32) {
    float s = s_part[tid][0] + s_part[tid][1] + s_part[tid][2] + s_part[tid][3];
    float kk = 0.0f;
    if (s > 0.0f) {
      float wv = lambertw0(s * 256.0f);
      kk = sqrtf(wv * 256.0f / s);
    }
    k_lds[tid] = kk;
  }
  __syncthreads();
#pragma unroll
  for (int fi = 0; fi < 16; ++fi) {
    int ch = fi >> 1, e = fi & 1;
    int col = (ch * 8 + q + 4 * e) * 16 + (lane & 15);
#pragma unroll
    for (int i = 0; i < 4; ++i) {
      int r = m * 16 + ((lane >> 4) << 2) + i;
      uo[(size_t)(rowbase + r) * C_ + col] = -k_lds[r] * fr[fi][i];
    }
  }
}

extern "C" void kernel_launch(void* const* d_in, const int* in_sizes, int n_in,
                              void* d_out, int out_size, void* d_ws, size_t ws_size,
                              hipStream_t stream) {
  const float* z  = (const float*)d_in[0];
  const float* t  = (const float*)d_in[1];
  const float* W1 = (const float*)d_in[2];
  const float* b1 = (const float*)d_in[3];
  const float* W2 = (const float*)d_in[4];
  const float* b2 = (const float*)d_in[5];
  const float* W3 = (const float*)d_in[6];
  const float* b3 = (const float*)d_in[7];
  float* out = (float*)d_out;
  unsigned char* ws = (unsigned char*)d_ws;
  float* part = (float*)(ws + OFF_part);   // 16 MB fp32 partials in workspace

  constexpr int PREP_ELEMS = NP_ * S_ + NP_ * NP_ + C_ * NP_ + C_;
  k0_prep<<<(PREP_ELEMS + 255) / 256, 256, 0, stream>>>(W1, W2, W3, b3, ws);
  k1_gemm1<<<B_ / 32 * NSPLIT_, 256, 0, stream>>>(z, ws, part);
  k2_fused<<<B_ / 32, 512, 0, stream>>>(part, t, W1, b1, b2, ws, out);
}

// Round 5
// 51.467 us; speedup vs baseline: 1.1483x; 1.0085x over previous
//
#include <hip/hip_runtime.h>

#define DEV __device__ __forceinline__

typedef __bf16 bf16x8 __attribute__((ext_vector_type(8)));
typedef float f32x4 __attribute__((ext_vector_type(4)));
typedef short s16x8 __attribute__((ext_vector_type(8)));
typedef unsigned short u16x8 __attribute__((ext_vector_type(8)));

constexpr int B_ = 8192;   // batch
constexpr int S_ = 3072;   // z dim
constexpr int H_ = 100;    // hidden
constexpr int NP_ = 128;   // padded hidden
constexpr int C_ = 1024;   // control dim
constexpr int KS_ = 64;    // K-step for GEMM1
constexpr int NSPLIT_ = 4; // K-split factor
constexpr int KSP_ = S_ / NSPLIT_;       // 768 per split
constexpr int NIT_ = KSP_ / KS_;         // 12 iters per block (even)

// workspace layout (bytes)
constexpr size_t OFF_W1b = 0;                                   // [128 n][3072 k] bf16
constexpr size_t OFF_W2b = OFF_W1b + (size_t)NP_ * S_ * 2;      // [128 n][128 k] bf16
constexpr size_t OFF_W3c = OFF_W2b + (size_t)NP_ * NP_ * 2;     // [1024 n][128 k] bf16
constexpr size_t OFF_b3c = OFF_W3c + (size_t)C_ * NP_ * 2;      // [1024] f32
constexpr size_t OFF_part = OFF_b3c + (size_t)C_ * 4;           // [4][8192][128] f32 partials

DEV unsigned short f2bf(float f) {
  union { float f; unsigned u; } x; x.f = f;
  return (unsigned short)((x.u + 0x7FFFu + ((x.u >> 16) & 1u)) >> 16);
}

DEV float lambertw0(float x) {
  float w = log1pf(x);
#pragma unroll
  for (int i = 0; i < 10; ++i) {
    float ew = expf(w);
    float f = fmaf(w, ew, -x);
    float wp1 = w + 1.0f;
    float den = ew * wp1 - (w + 2.0f) * f / (2.0f * wp1);
    w = w - f / den;
  }
  return w;
}

// ---------------- prep: pack weights into bf16 n-major padded layouts ----------------
__global__ void k0_prep(const float* __restrict__ W1, const float* __restrict__ W2,
                        const float* __restrict__ W3, const float* __restrict__ b3,
                        unsigned char* __restrict__ ws) {
  int idx = blockIdx.x * 256 + threadIdx.x;
  constexpr int R1 = NP_ * S_;
  constexpr int R2 = R1 + NP_ * NP_;
  constexpr int R3 = R2 + C_ * NP_;
  constexpr int R4 = R3 + C_;
  if (idx < R1) {
    int n = idx / S_, k = idx - n * S_;
    float v = (n < H_) ? W1[(size_t)(k + 1) * H_ + n] : 0.0f;  // row 0 of W1 = t weights
    ((unsigned short*)(ws + OFF_W1b))[idx] = f2bf(v);
  } else if (idx < R2) {
    int j = idx - R1;
    int n = j >> 7, k = j & 127;
    float v = (n < H_ && k < H_) ? W2[(size_t)k * H_ + n] : 0.0f;
    ((unsigned short*)(ws + OFF_W2b))[j] = f2bf(v);
  } else if (idx < R3) {
    int j = idx - R2;
    int n = j >> 7, k = j & 127;
    float v = 0.0f;
    if (k < H_) {
      int a = n >> 2, cmp = n & 3;
      const float* row = W3 + (size_t)k * S_ + a * 12;
      v = (cmp == 0) ? 2.0f * (row[6] + row[7] + row[8]) : row[8 + cmp];  // /MASS = *2
    }
    ((unsigned short*)(ws + OFF_W3c))[j] = f2bf(v);
  } else if (idx < R4) {
    int n = idx - R3;
    int a = n >> 2, cmp = n & 3;
    const float* row = b3 + a * 12;
    float v = (cmp == 0) ? 2.0f * (row[6] + row[7] + row[8]) : row[8 + cmp];
    ((float*)(ws + OFF_b3c))[n] = v;
  }
}

// ---------------- K1: partial[h] = z[:, h*768:(h+1)*768] @ W1b[:, same]^T ----------------
// grid 1024 = 256 row-tiles x 4 K-quarters; 256 thr (4 waves); 40KB LDS -> 4 blocks/CU.
// 2-deep register prefetch: at iter t, issue loads for tile t+2; write tile t+1 -> LDS.
__global__ __launch_bounds__(256, 4) void k1_gemm1(
    const float* __restrict__ z, const unsigned char* __restrict__ wsr,
    float* __restrict__ part) {
  __shared__ __align__(16) unsigned char lds[40 * 1024];
  unsigned char* ldsA = lds;          // 2 x 4KB  ([32 r][64 k] bf16, swizzled)
  unsigned char* ldsB = lds + 8192;   // 2 x 16KB ([128 n][64 k] bf16, swizzled)

  const int tid = threadIdx.x;
  const int lane = tid & 63;
  const int w = tid >> 6;
  const int m = w & 1;
  const int q = w >> 1;
  const int bid = blockIdx.x;
  const int rt = bid >> 2;
  const int h = bid & 3;
  const int rowbase = rt * 32;
  const int k0 = h * KSP_;

  const unsigned short* W1b = (const unsigned short*)(wsr + OFF_W1b);

  const int zrow = tid >> 3;              // 0..31
  const int zk8 = (tid & 7) * 8;          // 0..56 (8 floats per thread)
  const float* zp = z + (size_t)(rowbase + zrow) * S_ + k0 + zk8;
  const int bn = tid >> 3;                // 0..31 (+ s*32)
  const int bk16 = (tid & 7) * 8;
  const unsigned short* bp = W1b + (size_t)bn * S_ + k0 + bk16;

  const int aswz = ((zrow & 7) << 4);
  const int abyte = zrow * 128 + zk8 * 2;
  const int bswz = ((bn & 7) << 4);
  const int bbyte0 = bn * 128 + bk16 * 2;

  const int r0 = m * 16 + (lane & 15);
  const int kb0 = (lane >> 4) * 16;

  f32x4 acc[4];
#pragma unroll
  for (int e = 0; e < 4; ++e) acc[e] = f32x4{0.f, 0.f, 0.f, 0.f};

#define STAGE_A(dst, ZA, ZB) do {                                            \
    u16x8 av;                                                                \
    av[0] = f2bf((ZA).x); av[1] = f2bf((ZA).y);                              \
    av[2] = f2bf((ZA).z); av[3] = f2bf((ZA).w);                              \
    av[4] = f2bf((ZB).x); av[5] = f2bf((ZB).y);                              \
    av[6] = f2bf((ZB).z); av[7] = f2bf((ZB).w);                              \
    *(u16x8*)((dst) + (abyte ^ aswz)) = av;                                  \
  } while (0)

#define STAGE_B(dst, V0, V1, V2, V3) do {                                    \
    *(s16x8*)((dst) + ((bbyte0 + 0 * 4096) ^ bswz)) = (V0);                  \
    *(s16x8*)((dst) + ((bbyte0 + 1 * 4096) ^ bswz)) = (V1);                  \
    *(s16x8*)((dst) + ((bbyte0 + 2 * 4096) ^ bswz)) = (V2);                  \
    *(s16x8*)((dst) + ((bbyte0 + 3 * 4096) ^ bswz)) = (V3);                  \
  } while (0)

#define ISSUE(ko, ZA, ZB, V0, V1, V2, V3) do {                               \
    (ZA) = *(const float4*)(zp + (ko));                                      \
    (ZB) = *(const float4*)(zp + (ko) + 4);                                  \
    (V0) = *(const s16x8*)(bp + (ko));                                       \
    (V1) = *(const s16x8*)(bp + (ko) + (size_t)32 * S_);                     \
    (V2) = *(const s16x8*)(bp + (ko) + (size_t)64 * S_);                     \
    (V3) = *(const s16x8*)(bp + (ko) + (size_t)96 * S_);                     \
  } while (0)

#define COMPUTE(Ac, Bc) do {                                                 \
    bf16x8 a0 = *(const bf16x8*)((Ac) + ((r0 * 128 + 0 + kb0) ^ ((r0 & 7) << 4)));   \
    bf16x8 a1 = *(const bf16x8*)((Ac) + ((r0 * 128 + 64 + kb0) ^ ((r0 & 7) << 4)));  \
    _Pragma("unroll")                                                        \
    for (int e = 0; e < 4; ++e) {                                            \
      int n = q * 64 + e * 16 + (lane & 15);                                 \
      bf16x8 bb0 = *(const bf16x8*)((Bc) + ((n * 128 + 0 + kb0) ^ ((n & 7) << 4)));  \
      bf16x8 bb1 = *(const bf16x8*)((Bc) + ((n * 128 + 64 + kb0) ^ ((n & 7) << 4))); \
      acc[e] = __builtin_amdgcn_mfma_f32_16x16x32_bf16(a0, bb0, acc[e], 0, 0, 0);    \
      acc[e] = __builtin_amdgcn_mfma_f32_16x16x32_bf16(a1, bb1, acc[e], 0, 0, 0);    \
    }                                                                        \
  } while (0)

  float4 za0, zb0, za1, zb1;
  s16x8 b00, b01, b02, b03, b10, b11, b12, b13;

  // prologue: tile0 -> LDS[0]; issue tile1 -> set0
  {
    float4 za = *(const float4*)(zp);
    float4 zb = *(const float4*)(zp + 4);
    s16x8 v0 = *(const s16x8*)(bp);
    s16x8 v1 = *(const s16x8*)(bp + (size_t)32 * S_);
    s16x8 v2 = *(const s16x8*)(bp + (size_t)64 * S_);
    s16x8 v3 = *(const s16x8*)(bp + (size_t)96 * S_);
    STAGE_A(ldsA, za, zb);
    STAGE_B(ldsB, v0, v1, v2, v3);
  }
  ISSUE(KS_, za0, zb0, b00, b01, b02, b03);
  __syncthreads();

  for (int tt = 0; tt < NIT_; tt += 2) {
    // even iter t = tt: LDS[0] current; set0 holds tile t+1; issue set1 <- t+2
    {
      const int t = tt;
      if (t + 2 < NIT_) ISSUE((t + 2) * KS_, za1, zb1, b10, b11, b12, b13);
      COMPUTE(ldsA, ldsB);
      if (t + 1 < NIT_) {
        STAGE_A(ldsA + 4096, za0, zb0);
        STAGE_B(ldsB + 16384, b00, b01, b02, b03);
      }
      __syncthreads();
    }
    // odd iter t = tt+1: LDS[1] current; set1 holds tile t+1; issue set0 <- t+2
    {
      const int t = tt + 1;
      if (t + 2 < NIT_) ISSUE((t + 2) * KS_, za0, zb0, b00, b01, b02, b03);
      COMPUTE(ldsA + 4096, ldsB + 16384);
      if (t + 1 < NIT_) {
        STAGE_A(ldsA, za1, zb1);
        STAGE_B(ldsB, b10, b11, b12, b13);
      }
      __syncthreads();
    }
  }
#undef STAGE_A
#undef STAGE_B
#undef ISSUE
#undef COMPUTE

  float* pout = part + (size_t)h * B_ * NP_;
#pragma unroll
  for (int e = 0; e < 4; ++e) {
    int col = q * 64 + e * 16 + (lane & 15);
#pragma unroll
    for (int i = 0; i < 4; ++i) {
      int r = m * 16 + ((lane >> 4) << 2) + i;
      pout[(size_t)(rowbase + r) * NP_ + col] = acc[e][i];
    }
  }
}

// ---------------- K2 fused: partial-reduce + GEMM2 + GEMM3 + LambertW head -------------
// 256 blocks x 512 thr (8 waves). Phase1: h1=tanh(sum part + b1 + t*w1t) -> ldsA.
// GEMM2 (W2 in ldsB[1]) -> h2 -> ldsA. GEMM3 streams W3c (8 dbuf chunks).
__global__ __launch_bounds__(512, 2) void k2_fused(
    const float* __restrict__ part, const float* __restrict__ t,
    const float* __restrict__ W1, const float* __restrict__ b1,
    const float* __restrict__ b2, const unsigned char* __restrict__ wsr,
    float* __restrict__ uo) {
  __shared__ __align__(16) unsigned char ldsA[8192];        // h1/h2 tile [32][128] bf16 swz
  __shared__ __align__(16) unsigned char ldsB[2][32768];    // W2 / W3c chunks
  __shared__ float s_part[32][4];
  __shared__ float k_lds[32];

  const int tid = threadIdx.x;
  const int lane = tid & 63;
  const int w = tid >> 6;
  const int m = w & 1;
  const int q = w >> 1;
  const int rowbase = blockIdx.x * 32;

  const unsigned short* W2b = (const unsigned short*)(wsr + OFF_W2b);
  const unsigned short* W3cb = (const unsigned short*)(wsr + OFF_W3c);
  const float* b3c = (const float*)(wsr + OFF_b3c);

  // phase 1: reduce partials + b1 + t*w1t, tanh -> ldsA (h1)
  {
    const int row = tid >> 4;           // 0..31
    const int col0 = (tid & 15) * 8;    // 0..120
    const float* p0 = part + (size_t)(rowbase + row) * NP_ + col0;
    f32x4 v[2];
#pragma unroll
    for (int p = 0; p < 2; ++p) {
      v[p] = *(const f32x4*)(p0 + p * 4);
#pragma unroll
      for (int hh = 1; hh < NSPLIT_; ++hh) {
        f32x4 u2 = *(const f32x4*)(p0 + (size_t)hh * B_ * NP_ + p * 4);
        v[p][0] += u2[0]; v[p][1] += u2[1]; v[p][2] += u2[2]; v[p][3] += u2[3];
      }
    }
    const float tv = t[rowbase + row];
    u16x8 o;
#pragma unroll
    for (int j = 0; j < 8; ++j) {
      int col = col0 + j;
      float b1c = (col < H_) ? b1[col] : 0.0f;
      float w1t = (col < H_) ? W1[col] : 0.0f;
      float pre = v[j >> 2][j & 3] + b1c + tv * w1t;
      o[j] = f2bf(tanhf(pre));
    }
    *(u16x8*)(ldsA + ((row * 256 + col0 * 2) ^ ((row & 7) << 4))) = o;
  }
  // stage W2 -> ldsB[1], W3c chunk0 -> ldsB[0] (2048 16B-chunks each; 512 thr x 4)
#pragma unroll
  for (int s = 0; s < 4; ++s) {
    int p = s * 512 + tid;
    int n = p >> 4, k16 = p & 15;
    s16x8 v2 = *(const s16x8*)(W2b + n * 128 + k16 * 8);
    *(s16x8*)(ldsB[1] + ((n * 256 + k16 * 16) ^ ((n & 7) << 4))) = v2;
    s16x8 v3 = *(const s16x8*)(W3cb + (size_t)n * NP_ + k16 * 8);
    *(s16x8*)(ldsB[0] + ((n * 256 + k16 * 16) ^ ((n & 7) << 4))) = v3;
  }
  if (tid < 128) s_part[tid >> 2][tid & 3] = 0.0f;
  __syncthreads();

  const int r0 = m * 16 + (lane & 15);
  const int kb0 = (lane >> 4) * 16;

  // GEMM2: K=128, cols split over 8 waves as (q*2+e)*16
  f32x4 acc2[2];
  acc2[0] = f32x4{0.f, 0.f, 0.f, 0.f};
  acc2[1] = f32x4{0.f, 0.f, 0.f, 0.f};
#pragma unroll
  for (int ks = 0; ks < 4; ++ks) {
    bf16x8 a = *(const bf16x8*)(ldsA + ((r0 * 256 + ks * 64 + kb0) ^ ((r0 & 7) << 4)));
#pragma unroll
    for (int e = 0; e < 2; ++e) {
      int n = (q * 2 + e) * 16 + (lane & 15);
      bf16x8 b = *(const bf16x8*)(ldsB[1] + ((n * 256 + ks * 64 + kb0) ^ ((n & 7) << 4)));
      acc2[e] = __builtin_amdgcn_mfma_f32_16x16x32_bf16(a, b, acc2[e], 0, 0, 0);
    }
  }
  __syncthreads();   // all h1/W2 reads done
  // h2 = tanh(acc2 + b2) -> ldsA (pad cols: acc=0, b2c=0 -> 0)
#pragma unroll
  for (int e = 0; e < 2; ++e) {
    int col = (q * 2 + e) * 16 + (lane & 15);
    float b2c = (col < H_) ? b2[col] : 0.0f;
#pragma unroll
    for (int i = 0; i < 4; ++i) {
      int r = m * 16 + ((lane >> 4) << 2) + i;
      float hh = tanhf(acc2[e][i] + b2c);
      *(unsigned short*)(ldsA + ((r * 256 + col * 2) ^ ((r & 7) << 4))) = f2bf(hh);
    }
  }
  __syncthreads();   // h2 visible to all

  // GEMM3: c = h2 @ W3c + b3c, streaming 8 chunks of 128 cols
  bf16x8 af[4];
#pragma unroll
  for (int ks = 0; ks < 4; ++ks)
    af[ks] = *(const bf16x8*)(ldsA + ((r0 * 256 + ks * 64 + kb0) ^ ((r0 & 7) << 4)));

  f32x4 fr[16];
#pragma unroll
  for (int i = 0; i < 16; ++i) fr[i] = f32x4{0.f, 0.f, 0.f, 0.f};

#pragma unroll 8
  for (int ch = 0; ch < 8; ++ch) {
    const int cur = ch & 1;
    const bool more = ch < 7;
    s16x8 st0, st1, st2, st3;
    if (more) {
      int base = (ch + 1) * 128;
      { int p = tid;            int n = p >> 4, k16 = p & 15; st0 = *(const s16x8*)(W3cb + (size_t)(base + n) * NP_ + k16 * 8); }
      { int p = 512 + tid;      int n = p >> 4, k16 = p & 15; st1 = *(const s16x8*)(W3cb + (size_t)(base + n) * NP_ + k16 * 8); }
      { int p = 1024 + tid;     int n = p >> 4, k16 = p & 15; st2 = *(const s16x8*)(W3cb + (size_t)(base + n) * NP_ + k16 * 8); }
      { int p = 1536 + tid;     int n = p >> 4, k16 = p & 15; st3 = *(const s16x8*)(W3cb + (size_t)(base + n) * NP_ + k16 * 8); }
    }
#pragma unroll
    for (int e = 0; e < 2; ++e) {
      int nloc = (q + 4 * e) * 16 + (lane & 15);
#pragma unroll
      for (int ks = 0; ks < 4; ++ks) {
        bf16x8 b = *(const bf16x8*)(ldsB[cur] + ((nloc * 256 + ks * 64 + kb0) ^ ((nloc & 7) << 4)));
        fr[ch * 2 + e] = __builtin_amdgcn_mfma_f32_16x16x32_bf16(af[ks], b, fr[ch * 2 + e], 0, 0, 0);
      }
    }
    if (more) {
      unsigned char* Bn = ldsB[cur ^ 1];
      { int p = tid;        int n = p >> 4, k16 = p & 15; *(s16x8*)(Bn + ((n * 256 + k16 * 16) ^ ((n & 7) << 4))) = st0; }
      { int p = 512 + tid;  int n = p >> 4, k16 = p & 15; *(s16x8*)(Bn + ((n * 256 + k16 * 16) ^ ((n & 7) << 4))) = st1; }
      { int p = 1024 + tid; int n = p >> 4, k16 = p & 15; *(s16x8*)(Bn + ((n * 256 + k16 * 16) ^ ((n & 7) << 4))) = st2; }
      { int p = 1536 + tid; int n = p >> 4, k16 = p & 15; *(s16x8*)(Bn + ((n * 256 + k16 * 16) ^ ((n & 7) << 4))) = st3; }
    }
    __syncthreads();
  }

  // bias, s = ||c||^2, k = f(W(s*256)), u = -k*c
#pragma unroll
  for (int fi = 0; fi < 16; ++fi) {
    int ch = fi >> 1, e = fi & 1;
    int col = (ch * 8 + q + 4 * e) * 16 + (lane & 15);
    float bc = b3c[col];
    fr[fi][0] += bc; fr[fi][1] += bc; fr[fi][2] += bc; fr[fi][3] += bc;
  }
#pragma unroll
  for (int i = 0; i < 4; ++i) {
    float v = 0.f;
#pragma unroll
    for (int fi = 0; fi < 16; ++fi) v += fr[fi][i] * fr[fi][i];
    v += __shfl_xor(v, 1);
    v += __shfl_xor(v, 2);
    v += __shfl_xor(v, 4);
    v += __shfl_xor(v, 8);
    if ((lane & 15) == 0) s_part[m * 16 + ((lane >> 4) << 2) + i][q] = v;
  }
  __syncthreads();
  if (tid < 32) {
    float s = s_part[tid][0] + s_part[tid][1] + s_part[tid][2] + s_part[tid][3];
    float kk = 0.0f;
    if (s > 0.0f) {
      float wv = lambertw0(s * 256.0f);
      kk = sqrtf(wv * 256.0f / s);
    }
    k_lds[tid] = kk;
  }
  __syncthreads();
#pragma unroll
  for (int fi = 0; fi < 16; ++fi) {
    int ch = fi >> 1, e = fi & 1;
    int col = (ch * 8 + q + 4 * e) * 16 + (lane & 15);
#pragma unroll
    for (int i = 0; i < 4; ++i) {
      int r = m * 16 + ((lane >> 4) << 2) + i;
      uo[(size_t)(rowbase + r) * C_ + col] = -k_lds[r] * fr[fi][i];
    }
  }
}

extern "C" void kernel_launch(void* const* d_in, const int* in_sizes, int n_in,
                              void* d_out, int out_size, void* d_ws, size_t ws_size,
                              hipStream_t stream) {
  const float* z  = (const float*)d_in[0];
  const float* t  = (const float*)d_in[1];
  const float* W1 = (const float*)d_in[2];
  const float* b1 = (const float*)d_in[3];
  const float* W2 = (const float*)d_in[4];
  const float* b2 = (const float*)d_in[5];
  const float* W3 = (const float*)d_in[6];
  const float* b3 = (const float*)d_in[7];
  float* out = (float*)d_out;
  unsigned char* ws = (unsigned char*)d_ws;
  float* part = (float*)(ws + OFF_part);   // 16 MB fp32 partials in workspace

  constexpr int PREP_ELEMS = NP_ * S_ + NP_ * NP_ + C_ * NP_ + C_;
  k0_prep<<<(PREP_ELEMS + 255) / 256, 256, 0, stream>>>(W1, W2, W3, b3, ws);
  k1_gemm1<<<B_ / 32 * NSPLIT_, 256, 0, stream>>>(z, ws, part);
  k2_fused<<<B_ / 32, 512, 0, stream>>>(part, t, W1, b1, b2, ws, out);
}